// Round 5
// baseline (438.837 us; speedup 1.0000x reference)
//
#include <hip/hip_runtime.h>
#include <hip/hip_bf16.h>
#include <math.h>

// MixerBlock on MI355X — R12: R11's 8-phase 256²/BK=64 core widened to
// 16 waves (1024 thr), 4×4 wave grid, 64×64 per wave (acc 64 VGPR).
// 4 waves/SIMD fill the barrier/lgkm bubbles that left R11 at 37%
// per-block efficiency with 2 waves/SIMD. Same swizzle (0 conflicts in
// R11), same counted-vmcnt ledger re-derived for 1-load units:
// stage plan {p0,p1:T1.A | p2,p3:N0.B | p4,p5:N0.A | p6,p7:N1.B},
// vmcnt(2) at p3/p7. k1/k2 keep the R9 128² core.
#define B_   64
#define P_   196
#define PPAD 224
#define C_   768
#define TM_  384
#define CM_  3072
#define EPSY 0.1f

typedef unsigned short u16;
typedef __attribute__((ext_vector_type(8))) short bf16x8;
typedef __attribute__((ext_vector_type(4))) float f32x4;

__device__ __forceinline__ float bf2f(u16 v) {
    return __uint_as_float(((unsigned int)v) << 16);
}
__device__ __forceinline__ u16 f2bf(float f) {
    unsigned int u = __float_as_uint(f);
    unsigned int rounding = 0x7FFFu + ((u >> 16) & 1u);
    return (u16)((u + rounding) >> 16);
}

__device__ __forceinline__ void gl_lds16(const u16* g, u16* l) {
    __builtin_amdgcn_global_load_lds(
        (const __attribute__((address_space(1))) unsigned int*)g,
        (__attribute__((address_space(3))) unsigned int*)l,
        16, 0, 0);
}

// ---------------- prep ----------------

__global__ __launch_bounds__(256) void k_prep_xT(const float* __restrict__ x,
                                                 u16* __restrict__ xT,
                                                 float* __restrict__ xn1) {
    __shared__ u16 tile[32][33];
    __shared__ float colsum[32];
    const int b = blockIdx.z, p0 = blockIdx.x * 32, c0 = blockIdx.y * 32;
    const int tx = threadIdx.x & 31, ty = threadIdx.x >> 5;
    if (threadIdx.x < 32) colsum[threadIdx.x] = 0.f;
    const float* xb = x + (size_t)b * P_ * C_;
    float s = 0.f;
    #pragma unroll
    for (int r = 0; r < 4; ++r) {
        int p = p0 + ty + r * 8;
        float v = (p < P_) ? xb[(size_t)p * C_ + c0 + tx] : 0.f;
        u16 h = f2bf(v);
        tile[ty + r * 8][tx] = h;
        float vb = bf2f(h);
        s = fmaf(vb, vb, s);
    }
    __syncthreads();
    u16* dst = xT + ((size_t)b * C_ + c0) * PPAD + p0;
    #pragma unroll
    for (int r = 0; r < 4; ++r) {
        int cl = ty + r * 8;
        dst[(size_t)cl * PPAD + tx] = tile[tx][cl];
    }
    atomicAdd(&colsum[tx], s);
    __syncthreads();
    if (threadIdx.x < 32)
        atomicAdd(&xn1[(size_t)b * C_ + c0 + threadIdx.x], colsum[threadIdx.x]);
}

__device__ __forceinline__ void pad_norm_body(const float* in, u16* outb, float* norm,
                                              int rows, int inlen, int outlen,
                                              int bid, int tid) {
    int wave = (bid * 256 + tid) >> 6;
    int lane = tid & 63;
    if (wave >= rows) return;
    const float* src = in + (size_t)wave * inlen;
    u16* dst = outb + (size_t)wave * outlen;
    float s = 0.f;
    for (int i = lane; i < outlen; i += 64) {
        float v = (i < inlen) ? src[i] : 0.f;
        u16 h = f2bf(v);
        dst[i] = h;
        float vv = bf2f(h);
        s = fmaf(vv, vv, s);
    }
    #pragma unroll
    for (int off = 32; off > 0; off >>= 1) s += __shfl_down(s, off, 64);
    if (lane == 0) norm[wave] = s;
}

__global__ __launch_bounds__(256) void k_prep_weights(
    const float* __restrict__ tw, u16* __restrict__ twb, float* __restrict__ twn,
    const float* __restrict__ cw, u16* __restrict__ cwb, float* __restrict__ cwn,
    const float* __restrict__ w2, u16* __restrict__ w2b,
    const float* __restrict__ w4, u16* __restrict__ w4b) {
    int bid = blockIdx.x, tid = threadIdx.x;
    if (bid < 96) {
        pad_norm_body(tw, twb, twn, TM_, P_, PPAD, bid, tid);
    } else if (bid < 864) {
        pad_norm_body(cw, cwb, cwn, CM_, C_, C_, bid - 96, tid);
    } else if (bid < 1248) {
        int idx = (bid - 864) * 256 + tid;
        int row = idx / TM_;
        w2b[idx] = (row < P_) ? f2bf(w2[(size_t)row * TM_ + (idx % TM_)]) : (u16)0;
    } else {
        int idx = (bid - 1248) * 256 + tid;
        float4 v = ((const float4*)w4)[idx];
        ushort4 o;
        o.x = f2bf(v.x); o.y = f2bf(v.y); o.z = f2bf(v.z); o.w = f2bf(v.w);
        ((ushort4*)w4b)[idx] = o;
    }
}

// ---------------- R9 128x128 core (kept for k1/k2) ----------------
__device__ __forceinline__ void mfma_mainloop(
    const u16* __restrict__ A, const u16* __restrict__ B,
    int lda, int ldb, int kiters,
    f32x4 (&acc)[4][4], u16* As, u16* Bs) {
    const int t = threadIdx.x;
    const int w = t >> 6, l = t & 63;
    const int quad = l >> 4, l15 = l & 15;
    const int row0 = t >> 2, kc = (t & 3) * 8;

    const u16* pa0 = A + (size_t)row0 * lda + kc;
    const u16* pa1 = A + (size_t)(64 + row0) * lda + kc;
    const u16* pb0 = B + (size_t)row0 * ldb + kc;
    const u16* pb1 = B + (size_t)(64 + row0) * ldb + kc;

    u16* ldsA0 = As + w * 512;
    u16* ldsA1 = As + 2048 + w * 512;
    u16* ldsB0 = Bs + w * 512;
    u16* ldsB1 = Bs + 2048 + w * 512;

#define STAGE_(bsel, koff)                          \
    do {                                            \
        const int nb_ = (bsel) * 4096;              \
        gl_lds16(pa0 + (koff), ldsA0 + nb_);        \
        gl_lds16(pa1 + (koff), ldsA1 + nb_);        \
        gl_lds16(pb0 + (koff), ldsB0 + nb_);        \
        gl_lds16(pb1 + (koff), ldsB1 + nb_);        \
    } while (0)

    STAGE_(0, 0);
    if (kiters > 1) {
        STAGE_(1, 32);
        asm volatile("s_waitcnt vmcnt(4)" ::: "memory");
    } else {
        asm volatile("s_waitcnt vmcnt(0)" ::: "memory");
    }
    __builtin_amdgcn_s_barrier();

    int cur = 0;
    int koff = 64;
    for (int it = 0; it < kiters; ++it) {
        const u16* Aw = As + cur * 4096 + (w >> 1) * 2048;
        const u16* Bw = Bs + cur * 4096 + (w & 1) * 2048;
        bf16x8 af[4], bfr[4];
        #pragma unroll
        for (int i = 0; i < 4; ++i)
            af[i] = *(const bf16x8*)(Aw + ((i * 16 + l15) * 32 + quad * 8));
        #pragma unroll
        for (int j = 0; j < 4; ++j)
            bfr[j] = *(const bf16x8*)(Bw + ((j * 16 + l15) * 32 + quad * 8));
        asm volatile("s_waitcnt lgkmcnt(0)" ::: "memory");
        __builtin_amdgcn_sched_barrier(0);
        __builtin_amdgcn_s_barrier();
        const bool more2 = (it + 2 < kiters);
        if (more2) { STAGE_(cur, koff); koff += 32; }
        __builtin_amdgcn_s_setprio(1);
        #pragma unroll
        for (int i = 0; i < 4; ++i)
            #pragma unroll
            for (int j = 0; j < 4; ++j)
                acc[i][j] = __builtin_amdgcn_mfma_f32_16x16x32_bf16(af[i], bfr[j], acc[i][j], 0, 0, 0);
        __builtin_amdgcn_s_setprio(0);
        if (it + 1 < kiters) {
            if (more2) asm volatile("s_waitcnt vmcnt(4)" ::: "memory");
            else       asm volatile("s_waitcnt vmcnt(0)" ::: "memory");
            __builtin_amdgcn_s_barrier();
        }
        cur ^= 1;
    }
#undef STAGE_
}

#define MFMA_CORE(AP, BP, LDA, LDB, KITERS)                              \
    __shared__ u16 As[2 * 128 * 32];                                     \
    __shared__ u16 Bs[2 * 128 * 32];                                     \
    const int t = threadIdx.x;                                           \
    const int wid = t >> 6, lane = t & 63;                               \
    const int quad = lane >> 4, l15 = lane & 15;                         \
    f32x4 acc[4][4];                                                     \
    _Pragma("unroll")                                                    \
    for (int i = 0; i < 4; ++i)                                          \
        _Pragma("unroll")                                                \
        for (int j = 0; j < 4; ++j) acc[i][j] = (f32x4){0.f,0.f,0.f,0.f};\
    mfma_mainloop(AP, BP, LDA, LDB, KITERS, acc, As, Bs);                \
    const int rbase = m0 + (wid >> 1) * 64;                              \
    const int cbase = n0 + (wid & 1) * 64;

// ---------------- R12 16-wave 8-phase 256x256 core, BK=64 ----------------
// LDS: A [2][256][64] at elem 0 (32768), B at 32768. 131072 B total.
// Swizzle: LDS[r][slot] = G[r][slot ^ (r&7)] (8-elem slots). Staging is
// linear-dest gl_lds16 (1/thread/phase, 16KB units = 128 rows) with
// pre-swizzled source col; reads XOR the slot.
#define PH_MID()  do { __builtin_amdgcn_sched_barrier(0);                 \
    __builtin_amdgcn_s_barrier();                                         \
    asm volatile("s_waitcnt lgkmcnt(0)" ::: "memory");                    \
    __builtin_amdgcn_sched_barrier(0);                                    \
    __builtin_amdgcn_s_setprio(1); } while (0)
#define PH_END()  do { __builtin_amdgcn_s_setprio(0);                     \
    __builtin_amdgcn_sched_barrier(0);                                    \
    __builtin_amdgcn_s_barrier(); } while (0)
#define PH_END_VM(n) do { __builtin_amdgcn_s_setprio(0);                  \
    asm volatile("s_waitcnt vmcnt(" #n ")" ::: "memory");                 \
    __builtin_amdgcn_sched_barrier(0);                                    \
    __builtin_amdgcn_s_barrier(); } while (0)

// stage one 128-row unit (A or B half h) of K-tile T into buffer d
#define STG16(isB, d, h, T)                                               \
    gl_lds16(((isB) ? gB : gA) + (size_t)((h) * 128 + srow) *             \
                 ((isB) ? ldb : lda) + (T) * 64 + scol,                   \
             smem + ((isB) ? 32768 : 0) + (d) * 16384 + (h) * 8192 + t * 8)

#define DSA16(d, mh, Ar)                                                  \
    _Pragma("unroll")                                                     \
    for (int mi = 0; mi < 2; ++mi) {                                      \
        Ar[mi][0] = *(const bf16x8*)(aB0 + (d) * 16384 + ((mh) * 2 + mi) * 1024); \
        Ar[mi][1] = *(const bf16x8*)(aB1 + (d) * 16384 + ((mh) * 2 + mi) * 1024); \
    }
#define DSB16(d, nh, Br)                                                  \
    _Pragma("unroll")                                                     \
    for (int ni = 0; ni < 2; ++ni) {                                      \
        Br[ni][0] = *(const bf16x8*)(bB0 + (d) * 16384 + ((nh) * 2 + ni) * 1024); \
        Br[ni][1] = *(const bf16x8*)(bB1 + (d) * 16384 + ((nh) * 2 + ni) * 1024); \
    }
#define MMQ16(mh, nh, Br)                                                 \
    _Pragma("unroll")                                                     \
    for (int kk = 0; kk < 2; ++kk)                                        \
        _Pragma("unroll")                                                 \
        for (int mi = 0; mi < 2; ++mi)                                    \
            _Pragma("unroll")                                             \
            for (int ni = 0; ni < 2; ++ni)                                \
                acc[(mh) * 2 + mi][(nh) * 2 + ni] =                       \
                    __builtin_amdgcn_mfma_f32_16x16x32_bf16(              \
                        a[mi][kk], Br[ni][kk],                            \
                        acc[(mh) * 2 + mi][(nh) * 2 + ni], 0, 0, 0);

__device__ __forceinline__ void mfma16w_mainloop(
    const u16* __restrict__ A, const u16* __restrict__ B,
    int lda, int ldb, int ntiles,
    f32x4 (&acc)[4][4], u16* smem) {
    const int t = threadIdx.x;
    const int w = t >> 6, lane = t & 63;
    const int wr = w >> 2, wc = w & 3;
    const int quad = lane >> 4, l15 = lane & 15;

    // staging: thread t covers elem t*8 of a 128-row x 64-col unit
    const int srow = t >> 3;                          // row in unit
    const int scol = (((t & 7) ^ (srow & 7)) << 3);   // pre-swizzled source col
    const u16* gA = A;
    const u16* gB = B;

    // reads: swizzled slot addressing
    const int q = (quad * 8) ^ ((l15 & 7) << 3);
    const u16* aB0 = smem + (wr * 64 + l15) * 64 + q;
    const u16* aB1 = smem + (wr * 64 + l15) * 64 + (q ^ 32);
    const u16* bB0 = smem + 32768 + (wc * 64 + l15) * 64 + q;
    const u16* bB1 = smem + 32768 + (wc * 64 + l15) * 64 + (q ^ 32);

    // prologue: T0 {B0,B1,A0,A1} -> buf0 ; T1 {B0,B1} -> buf1
    STG16(1, 0, 0, 0); STG16(1, 0, 1, 0);
    STG16(0, 0, 0, 0); STG16(0, 0, 1, 0);
    STG16(1, 1, 0, 1); STG16(1, 1, 1, 1);
    asm volatile("s_waitcnt vmcnt(2)" ::: "memory");
    __builtin_amdgcn_s_barrier();

    bf16x8 a[2][2], b[2][2], c[2][2];
    const int NI = ntiles >> 1;
    for (int i = 0; i < NI - 1; ++i) {
        const int T1 = 2 * i + 1, N0 = 2 * i + 2, N1 = 2 * i + 3;
        // p0
        DSA16(0, 0, a) DSB16(0, 0, b)
        STG16(0, 1, 0, T1);
        PH_MID(); MMQ16(0, 0, b) PH_END();
        // p1
        DSB16(0, 1, c)
        STG16(0, 1, 1, T1);
        PH_MID(); MMQ16(0, 1, c) PH_END();
        // p2
        DSA16(0, 1, a)
        STG16(1, 0, 0, N0);
        PH_MID(); MMQ16(1, 1, c) PH_END();
        // p3
        STG16(1, 0, 1, N0);
        PH_MID(); MMQ16(1, 0, b) PH_END_VM(2);
        // p4
        DSA16(1, 0, a) DSB16(1, 0, b)
        STG16(0, 0, 0, N0);
        PH_MID(); MMQ16(0, 0, b) PH_END();
        // p5
        DSB16(1, 1, c)
        STG16(0, 0, 1, N0);
        PH_MID(); MMQ16(0, 1, c) PH_END();
        // p6
        DSA16(1, 1, a)
        STG16(1, 1, 0, N1);
        PH_MID(); MMQ16(1, 1, c) PH_END();
        // p7
        STG16(1, 1, 1, N1);
        PH_MID(); MMQ16(1, 0, b) PH_END_VM(2);
    }
    // tail iteration (tiles ntiles-2, ntiles-1); stages only T1.A at p0/p1
    {
        const int T1 = ntiles - 1;
        DSA16(0, 0, a) DSB16(0, 0, b)
        STG16(0, 1, 0, T1);
        PH_MID(); MMQ16(0, 0, b) PH_END();
        DSB16(0, 1, c)
        STG16(0, 1, 1, T1);
        PH_MID(); MMQ16(0, 1, c) PH_END();
        DSA16(0, 1, a)
        PH_MID(); MMQ16(1, 1, c) PH_END();
        PH_MID(); MMQ16(1, 0, b) PH_END_VM(0);
        DSA16(1, 0, a) DSB16(1, 0, b)
        PH_MID(); MMQ16(0, 0, b) PH_END();
        DSB16(1, 1, c)
        PH_MID(); MMQ16(0, 1, c) PH_END();
        DSA16(1, 1, a)
        PH_MID(); MMQ16(1, 1, c) PH_END();
        PH_MID(); MMQ16(1, 0, b)
        __builtin_amdgcn_s_setprio(0);
    }
}

// k1: h1[(b*C+c)][t] = yat(xT, twb); M=49152 N=384 K=224 (R9 core).
__global__ __launch_bounds__(256) void k1_token_yat(
    const u16* __restrict__ xT, const u16* __restrict__ twb,
    const float* __restrict__ tb, const float* __restrict__ twn,
    const float* __restrict__ xn1, const float* __restrict__ alpha, float sb,
    u16* __restrict__ h1) {
    const int m0 = (blockIdx.x + blockIdx.y * 8) * 128;
    const int n0 = blockIdx.z * 128;
    MFMA_CORE(xT + (size_t)m0 * PPAD, twb + (size_t)n0 * PPAD, PPAD, PPAD, PPAD / 32)
    float scale = powf(sqrtf(sb), alpha[0]);
    #pragma unroll
    for (int i = 0; i < 4; ++i) {
        #pragma unroll
        for (int j = 0; j < 4; ++j) {
            int col = cbase + j * 16 + l15;
            float bn = tb[col], wnn = twn[col];
            #pragma unroll
            for (int reg = 0; reg < 4; ++reg) {
                int row = rbase + i * 16 + quad * 4 + reg;
                float dnb = acc[i][j][reg];
                float dot = dnb + bn;
                float dist = wnn + xn1[row] - 2.f * dnb;
                h1[(size_t)row * TM_ + col] = f2bf(scale * dot * dot / (dist + EPSY));
            }
        }
    }
}

// k3: h3 = yat(x1b, cwb); M=12544 N=3072 K=768. 16-wave 8-phase 256² core.
// grid (8,7,12): mt = x + y*8 (XCD stripe, guard <49), n-tile = z.
__global__ __launch_bounds__(1024) void k3_chan_yat(
    const u16* __restrict__ x1b, const u16* __restrict__ cwb,
    const float* __restrict__ cb, const float* __restrict__ cwn,
    const float* __restrict__ xn2, const float* __restrict__ alpha, float sb,
    u16* __restrict__ h3) {
    __shared__ __align__(16) u16 smem[65536];
    const int mt = blockIdx.x + blockIdx.y * 8;
    if (mt >= (B_ * P_) / 256) return;
    const int m0 = mt * 256;
    const int n0 = blockIdx.z * 256;
    const int t = threadIdx.x;
    const int w = t >> 6, l = t & 63;
    const int wr = w >> 2, wc = w & 3;
    const int quad = l >> 4, l15 = l & 15;
    f32x4 acc[4][4];
    #pragma unroll
    for (int m = 0; m < 4; ++m)
        #pragma unroll
        for (int n = 0; n < 4; ++n) acc[m][n] = (f32x4){0.f, 0.f, 0.f, 0.f};
    mfma16w_mainloop(x1b + (size_t)m0 * C_, cwb + (size_t)n0 * C_,
                     C_, C_, C_ / 64, acc, smem);
    const int rbase = m0 + wr * 64;
    const int cbase = n0 + wc * 64;
    float scale = powf(sqrtf(sb), alpha[0]);
    #pragma unroll
    for (int m = 0; m < 4; ++m) {
        #pragma unroll
        for (int n = 0; n < 4; ++n) {
            int col = cbase + n * 16 + l15;
            float bn = cb[col], wnn = cwn[col];
            #pragma unroll
            for (int reg = 0; reg < 4; ++reg) {
                int row = rbase + m * 16 + quad * 4 + reg;
                float dnb = acc[m][n][reg];
                float dot = dnb + bn;
                float dist = wnn + xn2[row] - 2.f * dnb;
                h3[(size_t)row * CM_ + col] = f2bf(scale * dot * dot / (dist + EPSY));
            }
        }
    }
}

// k2: x1b = bf16(x + w2 . h1[b]^T + b2); fused xn2 row-norm atomics (R9 core).
__global__ __launch_bounds__(256) void k2_token_out(
    const u16* __restrict__ w2b, const u16* __restrict__ h1,
    const float* __restrict__ b2, const float* __restrict__ x,
    float* __restrict__ xn2, u16* __restrict__ x1b) {
    const int m0 = blockIdx.x * 128, n0 = blockIdx.y * 128;
    const u16* Bz = h1 + (size_t)blockIdx.z * C_ * TM_;
    MFMA_CORE(w2b + (size_t)m0 * TM_, Bz + (size_t)n0 * TM_, TM_, TM_, TM_ / 32)
    const float* rz = x + (size_t)blockIdx.z * P_ * C_;
    u16* oz = x1b + (size_t)blockIdx.z * P_ * C_;
    float* xrow = xn2 + (size_t)blockIdx.z * P_;
    #pragma unroll
    for (int i = 0; i < 4; ++i) {
        #pragma unroll
        for (int reg = 0; reg < 4; ++reg) {
            int row = rbase + i * 16 + quad * 4 + reg;
            if (row < P_) {
                float bm = b2[row];
                float s = 0.f;
                #pragma unroll
                for (int j = 0; j < 4; ++j) {
                    int col = cbase + j * 16 + l15;
                    float v = acc[i][j][reg] + bm + rz[(size_t)row * C_ + col];
                    u16 h = f2bf(v);
                    oz[(size_t)row * C_ + col] = h;
                    float vb = bf2f(h);
                    s = fmaf(vb, vb, s);
                }
                s += __shfl_xor(s, 1, 64);
                s += __shfl_xor(s, 2, 64);
                s += __shfl_xor(s, 4, 64);
                s += __shfl_xor(s, 8, 64);
                if (l15 == 0) atomicAdd(&xrow[row], s);
            }
        }
    }
}

// k4 split-K on 16-wave 8-phase core: grid (8,7,3*nsplit): n0=(z%3)*256, ks=z/3.
__global__ __launch_bounds__(1024) void k4_split(
    const u16* __restrict__ h3, const u16* __restrict__ w4b,
    u16* __restrict__ pbuf, int KK) {
    __shared__ __align__(16) u16 smem[65536];
    const int mt = blockIdx.x + blockIdx.y * 8;
    if (mt >= (B_ * P_) / 256) return;
    const int m0 = mt * 256;
    const int nz = blockIdx.z;
    const int n0 = (nz % 3) * 256;
    const int ks = nz / 3;
    const int kbase = ks * KK;
    const int t = threadIdx.x;
    const int w = t >> 6, l = t & 63;
    const int wr = w >> 2, wc = w & 3;
    const int quad = l >> 4, l15 = l & 15;
    f32x4 acc[4][4];
    #pragma unroll
    for (int m = 0; m < 4; ++m)
        #pragma unroll
        for (int n = 0; n < 4; ++n) acc[m][n] = (f32x4){0.f, 0.f, 0.f, 0.f};
    mfma16w_mainloop(h3 + (size_t)m0 * CM_ + kbase, w4b + (size_t)n0 * CM_ + kbase,
                     CM_, CM_, KK / 64, acc, smem);
    const int rbase = m0 + wr * 64;
    const int cbase = n0 + wc * 64;
    u16* dst = pbuf + (size_t)ks * ((size_t)B_ * P_ * C_);
    #pragma unroll
    for (int m = 0; m < 4; ++m) {
        #pragma unroll
        for (int n = 0; n < 4; ++n) {
            int col = cbase + n * 16 + l15;
            #pragma unroll
            for (int reg = 0; reg < 4; ++reg) {
                int row = rbase + m * 16 + quad * 4 + reg;
                dst[(size_t)row * C_ + col] = f2bf(acc[m][n][reg]);
            }
        }
    }
}

// reduce: out = sum(bf16 pbuf[0..NS-1]) + bf2f(x1b) + b4
template <int NS>
__global__ __launch_bounds__(256) void k4_reduce(
    float* __restrict__ outp, const u16* __restrict__ pbuf,
    const u16* __restrict__ x1b, const float* __restrict__ b4) {
    int idx = blockIdx.x * 256 + threadIdx.x;      // < B*P*C/4
    int c = (idx * 4) % C_;
    ushort4 r = ((const ushort4*)x1b)[idx];
    float4 o;
    o.x = bf2f(r.x) + b4[c + 0];
    o.y = bf2f(r.y) + b4[c + 1];
    o.z = bf2f(r.z) + b4[c + 2];
    o.w = bf2f(r.w) + b4[c + 3];
    const size_t stride4 = (size_t)B_ * P_ * C_ / 4;
    #pragma unroll
    for (int s = 0; s < NS; ++s) {
        ushort4 p = ((const ushort4*)pbuf)[idx + s * stride4];
        o.x += bf2f(p.x); o.y += bf2f(p.y); o.z += bf2f(p.z); o.w += bf2f(p.w);
    }
    ((float4*)outp)[idx] = o;
}

// fallback k4 (tiny ws): 128x64 tile BK=32
__global__ __launch_bounds__(256) void gemm_k4_fb(
    const u16* __restrict__ A, const u16* __restrict__ Bmat,
    const float* __restrict__ biasN, const u16* __restrict__ resB,
    float* __restrict__ Fout) {
    __shared__ u16 As[128 * 32];
    __shared__ u16 Bs[64 * 32];
    const int t = threadIdx.x;
    const int wid = t >> 6, lane = t & 63;
    const int quad = lane >> 4, l15 = lane & 15;
    const int m0 = blockIdx.x * 128, n0 = blockIdx.y * 64;
    f32x4 acc[4][2];
    #pragma unroll
    for (int i = 0; i < 4; ++i)
        #pragma unroll
        for (int j = 0; j < 2; ++j) acc[i][j] = (f32x4){0.f, 0.f, 0.f, 0.f};
    const u16* Aw = As + (wid >> 1) * (64 * 32);
    const u16* Bw = Bs + (wid & 1) * (32 * 32);
    const int arow = t >> 2, akc = (t & 3) * 8;
    for (int k0 = 0; k0 < CM_; k0 += 32) {
        gl_lds16(A + (size_t)(m0 + arow) * CM_ + k0 + akc,      As + wid * 512);
        gl_lds16(A + (size_t)(m0 + 64 + arow) * CM_ + k0 + akc, As + 2048 + wid * 512);
        gl_lds16(Bmat + (size_t)(n0 + arow) * CM_ + k0 + akc,   Bs + wid * 512);
        __syncthreads();
        bf16x8 af[4], bfr[2];
        #pragma unroll
        for (int i = 0; i < 4; ++i)
            af[i] = *(const bf16x8*)(Aw + ((i * 16 + l15) * 32 + quad * 8));
        #pragma unroll
        for (int j = 0; j < 2; ++j)
            bfr[j] = *(const bf16x8*)(Bw + ((j * 16 + l15) * 32 + quad * 8));
        #pragma unroll
        for (int i = 0; i < 4; ++i)
            #pragma unroll
            for (int j = 0; j < 2; ++j)
                acc[i][j] = __builtin_amdgcn_mfma_f32_16x16x32_bf16(af[i], bfr[j], acc[i][j], 0, 0, 0);
        __syncthreads();
    }
    const int rbase = m0 + (wid >> 1) * 64;
    const int cbase = n0 + (wid & 1) * 32;
    #pragma unroll
    for (int i = 0; i < 4; ++i) {
        #pragma unroll
        for (int j = 0; j < 2; ++j) {
            int col = cbase + j * 16 + l15;
            float bn = biasN[col];
            #pragma unroll
            for (int reg = 0; reg < 4; ++reg) {
                int row = rbase + i * 16 + quad * 4 + reg;
                float v = acc[i][j][reg] + bn + bf2f(resB[(size_t)row * C_ + col]);
                Fout[(size_t)row * C_ + col] = v;
            }
        }
    }
}

extern "C" void kernel_launch(void* const* d_in, const int* in_sizes, int n_in,
                              void* d_out, int out_size, void* d_ws, size_t ws_size,
                              hipStream_t stream) {
    const float* x  = (const float*)d_in[0];
    const float* tw = (const float*)d_in[1];
    const float* tb = (const float*)d_in[2];
    const float* ta = (const float*)d_in[3];
    const float* w2 = (const float*)d_in[4];
    const float* b2 = (const float*)d_in[5];
    const float* cw = (const float*)d_in[6];
    const float* cb = (const float*)d_in[7];
    const float* ca = (const float*)d_in[8];
    const float* w4 = (const float*)d_in[9];
    const float* b4 = (const float*)d_in[10];
    float* out = (float*)d_out;

    // ---- workspace layout (aliased) ----
    char* ws = (char*)d_ws;
    u16* h1 = (u16*)ws;                                    // B*C*TM (37.7 MB)
    u16* xT = (u16*)(ws + 37748736);                       // (B*C) x 224 (22 MB)
    u16* h3 = (u16*)ws;                                    // (B*P) x CM (77 MB)
    size_t off = 77070336;
    u16* x1b = (u16*)(ws + off); off += (size_t)B_ * P_ * C_ * 2;
    u16* twb = (u16*)(ws + off); off += (size_t)TM_ * PPAD * 2;
    u16* w2b = (u16*)(ws + off); off += (size_t)256 * TM_ * 2;
    u16* cwb = (u16*)(ws + off); off += (size_t)CM_ * C_ * 2;
    u16* w4b = (u16*)(ws + off); off += (size_t)C_ * CM_ * 2;
    float* xn1 = (float*)(ws + off); off += (size_t)B_ * C_ * 4;
    float* xn2 = (float*)(ws + off); off += (size_t)B_ * P_ * 4;
    float* twn = (float*)(ws + off); off += (size_t)TM_ * 4;
    float* cwn = (float*)(ws + off); off += (size_t)CM_ * 4;
    u16* pbuf = (u16*)(ws + off);                          // bf16 split-K partials
    const size_t psz = (size_t)B_ * P_ * C_ * 2;           // 19,267,584 per buffer

    int nsplit = 1;
    if (ws_size >= off + 4 * psz)      nsplit = 4;
    else if (ws_size >= off + 2 * psz) nsplit = 2;

    const float SBT = (float)TM_ / logf((float)TM_ + 1.0f);
    const float SBC = (float)CM_ / logf((float)CM_ + 1.0f);

    // ---- prep ----
    hipMemsetAsync(xn1, 0, (size_t)(B_ * C_ + B_ * P_) * 4, stream);
    k_prep_weights<<<3552, 256, 0, stream>>>(tw, twb, twn, cw, cwb, cwn,
                                             w2, w2b, w4, w4b);
    k_prep_xT<<<dim3(PPAD / 32, C_ / 32, B_), 256, 0, stream>>>(x, xT, xn1);

    // ---- k1: M=49152 N=384 K=224 ; XCD-swizzled grid (8,48,3) ----
    k1_token_yat<<<dim3(8, 48, 3), 256, 0, stream>>>(
        xT, twb, tb, twn, xn1, ta, SBT, h1);

    // ---- k2: M=256 N=768 K=384, per-batch ----
    k2_token_out<<<dim3(2, C_ / 128, B_), 256, 0, stream>>>(
        w2b, h1, b2, x, xn2, x1b);

    // ---- k3: M=12544 N=3072 K=768 ; 16-wave 8-phase 256², grid (8,7,12) ----
    k3_chan_yat<<<dim3(8, 7, 12), 1024, 0, stream>>>(
        x1b, cwb, cb, cwn, xn2, ca, SBC, h3);

    // ---- k4: M=12544 N=768 K=3072, split-K bf16 partials, 16-wave core ----
    if (nsplit > 1) {
        k4_split<<<dim3(8, 7, 3 * nsplit), 1024, 0, stream>>>(
            h3, w4b, pbuf, CM_ / nsplit);
        int n4 = B_ * P_ * C_ / 4;
        if (nsplit == 4)
            k4_reduce<4><<<(n4 + 255) / 256, 256, 0, stream>>>(out, pbuf, x1b, b4);
        else
            k4_reduce<2><<<(n4 + 255) / 256, 256, 0, stream>>>(out, pbuf, x1b, b4);
    } else {
        gemm_k4_fb<<<dim3(B_ * P_ / 128, C_ / 64), 256, 0, stream>>>(
            h3, w4b, b4, x1b, out);
    }
}

// Round 6
// 356.986 us; speedup vs baseline: 1.2293x; 1.2293x over previous
//
#include <hip/hip_runtime.h>
#include <hip/hip_bf16.h>
#include <math.h>

// MixerBlock on MI355X — R13: 8-phase fine-interleaved core (R11's validated
// schedule) at 128x128/BK=64/4-wave/64KB-LDS => 2 desynced blocks per CU
// (m114 overlap fills barrier bubbles; R11's 128KB tile ran 1 block/CU
// lockstep at MfmaUtil 24.5%). Stage ledger = R12's HW-validated plan
// {p0,p1:T1.A | p2,p3:N0.B | p4,p5:N0.A | p6,p7:N1.B}, counts x2 =>
// vmcnt(4) at p3/p7. Swizzle col^=(row&7)<<3 (0 conflicts in R11/R12).
// k1/k2 keep the R9 128²/BK=32 2-deep core.
#define B_   64
#define P_   196
#define PPAD 224
#define C_   768
#define TM_  384
#define CM_  3072
#define EPSY 0.1f

typedef unsigned short u16;
typedef __attribute__((ext_vector_type(8))) short bf16x8;
typedef __attribute__((ext_vector_type(4))) float f32x4;

__device__ __forceinline__ float bf2f(u16 v) {
    return __uint_as_float(((unsigned int)v) << 16);
}
__device__ __forceinline__ u16 f2bf(float f) {
    unsigned int u = __float_as_uint(f);
    unsigned int rounding = 0x7FFFu + ((u >> 16) & 1u);
    return (u16)((u + rounding) >> 16);
}

__device__ __forceinline__ void gl_lds16(const u16* g, u16* l) {
    __builtin_amdgcn_global_load_lds(
        (const __attribute__((address_space(1))) unsigned int*)g,
        (__attribute__((address_space(3))) unsigned int*)l,
        16, 0, 0);
}

// ---------------- prep ----------------

__global__ __launch_bounds__(256) void k_prep_xT(const float* __restrict__ x,
                                                 u16* __restrict__ xT,
                                                 float* __restrict__ xn1) {
    __shared__ u16 tile[32][33];
    __shared__ float colsum[32];
    const int b = blockIdx.z, p0 = blockIdx.x * 32, c0 = blockIdx.y * 32;
    const int tx = threadIdx.x & 31, ty = threadIdx.x >> 5;
    if (threadIdx.x < 32) colsum[threadIdx.x] = 0.f;
    const float* xb = x + (size_t)b * P_ * C_;
    float s = 0.f;
    #pragma unroll
    for (int r = 0; r < 4; ++r) {
        int p = p0 + ty + r * 8;
        float v = (p < P_) ? xb[(size_t)p * C_ + c0 + tx] : 0.f;
        u16 h = f2bf(v);
        tile[ty + r * 8][tx] = h;
        float vb = bf2f(h);
        s = fmaf(vb, vb, s);
    }
    __syncthreads();
    u16* dst = xT + ((size_t)b * C_ + c0) * PPAD + p0;
    #pragma unroll
    for (int r = 0; r < 4; ++r) {
        int cl = ty + r * 8;
        dst[(size_t)cl * PPAD + tx] = tile[tx][cl];
    }
    atomicAdd(&colsum[tx], s);
    __syncthreads();
    if (threadIdx.x < 32)
        atomicAdd(&xn1[(size_t)b * C_ + c0 + threadIdx.x], colsum[threadIdx.x]);
}

__device__ __forceinline__ void pad_norm_body(const float* in, u16* outb, float* norm,
                                              int rows, int inlen, int outlen,
                                              int bid, int tid) {
    int wave = (bid * 256 + tid) >> 6;
    int lane = tid & 63;
    if (wave >= rows) return;
    const float* src = in + (size_t)wave * inlen;
    u16* dst = outb + (size_t)wave * outlen;
    float s = 0.f;
    for (int i = lane; i < outlen; i += 64) {
        float v = (i < inlen) ? src[i] : 0.f;
        u16 h = f2bf(v);
        dst[i] = h;
        float vv = bf2f(h);
        s = fmaf(vv, vv, s);
    }
    #pragma unroll
    for (int off = 32; off > 0; off >>= 1) s += __shfl_down(s, off, 64);
    if (lane == 0) norm[wave] = s;
}

__global__ __launch_bounds__(256) void k_prep_weights(
    const float* __restrict__ tw, u16* __restrict__ twb, float* __restrict__ twn,
    const float* __restrict__ cw, u16* __restrict__ cwb, float* __restrict__ cwn,
    const float* __restrict__ w2, u16* __restrict__ w2b,
    const float* __restrict__ w4, u16* __restrict__ w4b) {
    int bid = blockIdx.x, tid = threadIdx.x;
    if (bid < 96) {
        pad_norm_body(tw, twb, twn, TM_, P_, PPAD, bid, tid);
    } else if (bid < 864) {
        pad_norm_body(cw, cwb, cwn, CM_, C_, C_, bid - 96, tid);
    } else if (bid < 1248) {
        int idx = (bid - 864) * 256 + tid;
        int row = idx / TM_;
        w2b[idx] = (row < P_) ? f2bf(w2[(size_t)row * TM_ + (idx % TM_)]) : (u16)0;
    } else {
        int idx = (bid - 1248) * 256 + tid;
        float4 v = ((const float4*)w4)[idx];
        ushort4 o;
        o.x = f2bf(v.x); o.y = f2bf(v.y); o.z = f2bf(v.z); o.w = f2bf(v.w);
        ((ushort4*)w4b)[idx] = o;
    }
}

// ---------------- R9 128x128 core (kept for k1/k2) ----------------
__device__ __forceinline__ void mfma_mainloop(
    const u16* __restrict__ A, const u16* __restrict__ B,
    int lda, int ldb, int kiters,
    f32x4 (&acc)[4][4], u16* As, u16* Bs) {
    const int t = threadIdx.x;
    const int w = t >> 6, l = t & 63;
    const int quad = l >> 4, l15 = l & 15;
    const int row0 = t >> 2, kc = (t & 3) * 8;

    const u16* pa0 = A + (size_t)row0 * lda + kc;
    const u16* pa1 = A + (size_t)(64 + row0) * lda + kc;
    const u16* pb0 = B + (size_t)row0 * ldb + kc;
    const u16* pb1 = B + (size_t)(64 + row0) * ldb + kc;

    u16* ldsA0 = As + w * 512;
    u16* ldsA1 = As + 2048 + w * 512;
    u16* ldsB0 = Bs + w * 512;
    u16* ldsB1 = Bs + 2048 + w * 512;

#define STAGE_(bsel, koff)                          \
    do {                                            \
        const int nb_ = (bsel) * 4096;              \
        gl_lds16(pa0 + (koff), ldsA0 + nb_);        \
        gl_lds16(pa1 + (koff), ldsA1 + nb_);        \
        gl_lds16(pb0 + (koff), ldsB0 + nb_);        \
        gl_lds16(pb1 + (koff), ldsB1 + nb_);        \
    } while (0)

    STAGE_(0, 0);
    if (kiters > 1) {
        STAGE_(1, 32);
        asm volatile("s_waitcnt vmcnt(4)" ::: "memory");
    } else {
        asm volatile("s_waitcnt vmcnt(0)" ::: "memory");
    }
    __builtin_amdgcn_s_barrier();

    int cur = 0;
    int koff = 64;
    for (int it = 0; it < kiters; ++it) {
        const u16* Aw = As + cur * 4096 + (w >> 1) * 2048;
        const u16* Bw = Bs + cur * 4096 + (w & 1) * 2048;
        bf16x8 af[4], bfr[4];
        #pragma unroll
        for (int i = 0; i < 4; ++i)
            af[i] = *(const bf16x8*)(Aw + ((i * 16 + l15) * 32 + quad * 8));
        #pragma unroll
        for (int j = 0; j < 4; ++j)
            bfr[j] = *(const bf16x8*)(Bw + ((j * 16 + l15) * 32 + quad * 8));
        asm volatile("s_waitcnt lgkmcnt(0)" ::: "memory");
        __builtin_amdgcn_sched_barrier(0);
        __builtin_amdgcn_s_barrier();
        const bool more2 = (it + 2 < kiters);
        if (more2) { STAGE_(cur, koff); koff += 32; }
        __builtin_amdgcn_s_setprio(1);
        #pragma unroll
        for (int i = 0; i < 4; ++i)
            #pragma unroll
            for (int j = 0; j < 4; ++j)
                acc[i][j] = __builtin_amdgcn_mfma_f32_16x16x32_bf16(af[i], bfr[j], acc[i][j], 0, 0, 0);
        __builtin_amdgcn_s_setprio(0);
        if (it + 1 < kiters) {
            if (more2) asm volatile("s_waitcnt vmcnt(4)" ::: "memory");
            else       asm volatile("s_waitcnt vmcnt(0)" ::: "memory");
            __builtin_amdgcn_s_barrier();
        }
        cur ^= 1;
    }
#undef STAGE_
}

#define MFMA_CORE(AP, BP, LDA, LDB, KITERS)                              \
    __shared__ u16 As[2 * 128 * 32];                                     \
    __shared__ u16 Bs[2 * 128 * 32];                                     \
    const int t = threadIdx.x;                                           \
    const int wid = t >> 6, lane = t & 63;                               \
    const int quad = lane >> 4, l15 = lane & 15;                         \
    f32x4 acc[4][4];                                                     \
    _Pragma("unroll")                                                    \
    for (int i = 0; i < 4; ++i)                                          \
        _Pragma("unroll")                                                \
        for (int j = 0; j < 4; ++j) acc[i][j] = (f32x4){0.f,0.f,0.f,0.f};\
    mfma_mainloop(AP, BP, LDA, LDB, KITERS, acc, As, Bs);                \
    const int rbase = m0 + (wid >> 1) * 64;                              \
    const int cbase = n0 + (wid & 1) * 64;

// ---------------- R13 4-wave 8-phase 128x128 core, BK=64 ----------------
// LDS elems: A [2][128][64] at 0 (16384), B at 16384. 65536 B total.
// Swizzle: LDS[r][c] = G[r][c ^ ((r&7)<<3)]. Units = 64 rows of A or B for
// one K-tile (8KB, 2 gl_lds16/thread). Reads per phase p0..p3 on buf0:
// {A.mh0+B.nh0, B.nh1, A.mh1, -}; A last read p2, B last read p1.
#define PH_MID()  do { __builtin_amdgcn_sched_barrier(0);                 \
    __builtin_amdgcn_s_barrier();                                         \
    asm volatile("s_waitcnt lgkmcnt(0)" ::: "memory");                    \
    __builtin_amdgcn_sched_barrier(0);                                    \
    __builtin_amdgcn_s_setprio(1); } while (0)
#define PH_END()  do { __builtin_amdgcn_s_setprio(0);                     \
    __builtin_amdgcn_sched_barrier(0);                                    \
    __builtin_amdgcn_s_barrier(); } while (0)
#define PH_END_VM(n) do { __builtin_amdgcn_s_setprio(0);                  \
    asm volatile("s_waitcnt vmcnt(" #n ")" ::: "memory");                 \
    __builtin_amdgcn_sched_barrier(0);                                    \
    __builtin_amdgcn_s_barrier(); } while (0)

#define STG4(isB, d, h, T)                                                \
    do {                                                                  \
        const int ld_ = (isB) ? ldb : lda;                                \
        const u16* g_ = ((isB) ? gB : gA) +                               \
            (size_t)((h) * 64 + srow) * ld_ + (T) * 64 + scol;            \
        u16* s_ = smem + ((isB) ? 16384 : 0) + (d) * 8192 + (h) * 4096 + t * 8; \
        gl_lds16(g_, s_);                                                 \
        gl_lds16(g_ + (size_t)32 * ld_, s_ + 2048);                       \
    } while (0)

#define DSA4(d, mh, Ar)                                                   \
    _Pragma("unroll")                                                     \
    for (int mi = 0; mi < 2; ++mi) {                                      \
        Ar[mi][0] = *(const bf16x8*)(aB0 + (d) * 8192 + ((mh) * 2 + mi) * 1024); \
        Ar[mi][1] = *(const bf16x8*)(aB1 + (d) * 8192 + ((mh) * 2 + mi) * 1024); \
    }
#define DSB4(d, nh, Br)                                                   \
    _Pragma("unroll")                                                     \
    for (int ni = 0; ni < 2; ++ni) {                                      \
        Br[ni][0] = *(const bf16x8*)(bB0 + (d) * 8192 + ((nh) * 2 + ni) * 1024); \
        Br[ni][1] = *(const bf16x8*)(bB1 + (d) * 8192 + ((nh) * 2 + ni) * 1024); \
    }
#define MMQ4(mh, nh, Br)                                                  \
    _Pragma("unroll")                                                     \
    for (int kk = 0; kk < 2; ++kk)                                        \
        _Pragma("unroll")                                                 \
        for (int mi = 0; mi < 2; ++mi)                                    \
            _Pragma("unroll")                                             \
            for (int ni = 0; ni < 2; ++ni)                                \
                acc[(mh) * 2 + mi][(nh) * 2 + ni] =                       \
                    __builtin_amdgcn_mfma_f32_16x16x32_bf16(              \
                        a[mi][kk], Br[ni][kk],                            \
                        acc[(mh) * 2 + mi][(nh) * 2 + ni], 0, 0, 0);

__device__ __forceinline__ void mfma128_8p(
    const u16* __restrict__ gA, const u16* __restrict__ gB,
    int lda, int ldb, int ntiles,
    f32x4 (&acc)[4][4], u16* smem) {
    const int t = threadIdx.x;
    const int w = t >> 6, lane = t & 63;
    const int wr = w >> 1, wc = w & 1;
    const int quad = lane >> 4, l15 = lane & 15;

    // staging: thread t covers elems t*8 and 2048+t*8 of each 64x64 unit
    const int srow = t >> 3;                          // 0..31
    const int scol = (((t & 7) ^ (srow & 7)) << 3);   // pre-swizzled source col

    // reads: swizzled slot addressing
    const int q = (quad * 8) ^ ((l15 & 7) << 3);
    const u16* aB0 = smem + (wr * 64 + l15) * 64 + q;
    const u16* aB1 = smem + (wr * 64 + l15) * 64 + (q ^ 32);
    const u16* bB0 = smem + 16384 + (wc * 64 + l15) * 64 + q;
    const u16* bB1 = smem + 16384 + (wc * 64 + l15) * 64 + (q ^ 32);

    // prologue: T0 {A0,A1,B0,B1} -> buf0 ; T1 {B0,B1} -> buf1 (12 loads)
    STG4(0, 0, 0, 0); STG4(0, 0, 1, 0);
    STG4(1, 0, 0, 0); STG4(1, 0, 1, 0);
    STG4(1, 1, 0, 1); STG4(1, 1, 1, 1);
    asm volatile("s_waitcnt vmcnt(4)" ::: "memory");   // retire T0 (8 loads)
    __builtin_amdgcn_s_barrier();

    bf16x8 a[2][2], b[2][2], c[2][2];
    const int NI = ntiles >> 1;
    for (int i = 0; i < NI - 1; ++i) {
        const int T1 = 2 * i + 1, N0 = 2 * i + 2, N1 = 2 * i + 3;
        // p0
        DSA4(0, 0, a) DSB4(0, 0, b)
        STG4(0, 1, 0, T1);
        PH_MID(); MMQ4(0, 0, b) PH_END();
        // p1
        DSB4(0, 1, c)
        STG4(0, 1, 1, T1);
        PH_MID(); MMQ4(0, 1, c) PH_END();
        // p2
        DSA4(0, 1, a)
        STG4(1, 0, 0, N0);
        PH_MID(); MMQ4(1, 1, c) PH_END();
        // p3
        STG4(1, 0, 1, N0);
        PH_MID(); MMQ4(1, 0, b) PH_END_VM(4);
        // p4
        DSA4(1, 0, a) DSB4(1, 0, b)
        STG4(0, 0, 0, N0);
        PH_MID(); MMQ4(0, 0, b) PH_END();
        // p5
        DSB4(1, 1, c)
        STG4(0, 0, 1, N0);
        PH_MID(); MMQ4(0, 1, c) PH_END();
        // p6
        DSA4(1, 1, a)
        STG4(1, 1, 0, N1);
        PH_MID(); MMQ4(1, 1, c) PH_END();
        // p7
        STG4(1, 1, 1, N1);
        PH_MID(); MMQ4(1, 0, b) PH_END_VM(4);
    }
    // tail: buf0 = tile ntiles-2, buf1 = tile ntiles-1; stage only buf1.A
    {
        const int Tl = ntiles - 1;
        DSA4(0, 0, a) DSB4(0, 0, b)
        STG4(0, 1, 0, Tl);
        PH_MID(); MMQ4(0, 0, b) PH_END();
        DSB4(0, 1, c)
        STG4(0, 1, 1, Tl);
        PH_MID(); MMQ4(0, 1, c) PH_END();
        DSA4(0, 1, a)
        PH_MID(); MMQ4(1, 1, c) PH_END();
        PH_MID(); MMQ4(1, 0, b) PH_END_VM(0);
        DSA4(1, 0, a) DSB4(1, 0, b)
        PH_MID(); MMQ4(0, 0, b) PH_END();
        DSB4(1, 1, c)
        PH_MID(); MMQ4(0, 1, c) PH_END();
        DSA4(1, 1, a)
        PH_MID(); MMQ4(1, 1, c) PH_END();
        PH_MID(); MMQ4(1, 0, b)
        __builtin_amdgcn_s_setprio(0);
    }
}

// k1: h1[(b*C+c)][t] = yat(xT, twb); M=49152 N=384 K=224 (R9 core).
__global__ __launch_bounds__(256) void k1_token_yat(
    const u16* __restrict__ xT, const u16* __restrict__ twb,
    const float* __restrict__ tb, const float* __restrict__ twn,
    const float* __restrict__ xn1, const float* __restrict__ alpha, float sb,
    u16* __restrict__ h1) {
    const int m0 = (blockIdx.x + blockIdx.y * 8) * 128;
    const int n0 = blockIdx.z * 128;
    MFMA_CORE(xT + (size_t)m0 * PPAD, twb + (size_t)n0 * PPAD, PPAD, PPAD, PPAD / 32)
    float scale = powf(sqrtf(sb), alpha[0]);
    #pragma unroll
    for (int i = 0; i < 4; ++i) {
        #pragma unroll
        for (int j = 0; j < 4; ++j) {
            int col = cbase + j * 16 + l15;
            float bn = tb[col], wnn = twn[col];
            #pragma unroll
            for (int reg = 0; reg < 4; ++reg) {
                int row = rbase + i * 16 + quad * 4 + reg;
                float dnb = acc[i][j][reg];
                float dot = dnb + bn;
                float dist = wnn + xn1[row] - 2.f * dnb;
                h1[(size_t)row * TM_ + col] = f2bf(scale * dot * dot / (dist + EPSY));
            }
        }
    }
}

// k3: h3 = yat(x1b, cwb); M=12544 N=3072 K=768. 4-wave 8-phase 128² core.
// grid (8,13,24): mt = x + y*8 (XCD stripe, guard <98), n-tile = z.
__global__ __launch_bounds__(256) void k3_chan_yat(
    const u16* __restrict__ x1b, const u16* __restrict__ cwb,
    const float* __restrict__ cb, const float* __restrict__ cwn,
    const float* __restrict__ xn2, const float* __restrict__ alpha, float sb,
    u16* __restrict__ h3) {
    __shared__ __align__(16) u16 smem[32768];
    const int mt = blockIdx.x + blockIdx.y * 8;
    if (mt >= (B_ * P_) / 128) return;
    const int m0 = mt * 128;
    const int n0 = blockIdx.z * 128;
    const int t = threadIdx.x;
    const int w = t >> 6, l = t & 63;
    const int wr = w >> 1, wc = w & 1;
    const int quad = l >> 4, l15 = l & 15;
    f32x4 acc[4][4];
    #pragma unroll
    for (int m = 0; m < 4; ++m)
        #pragma unroll
        for (int n = 0; n < 4; ++n) acc[m][n] = (f32x4){0.f, 0.f, 0.f, 0.f};
    mfma128_8p(x1b + (size_t)m0 * C_, cwb + (size_t)n0 * C_,
               C_, C_, C_ / 64, acc, smem);
    const int rbase = m0 + wr * 64;
    const int cbase = n0 + wc * 64;
    float scale = powf(sqrtf(sb), alpha[0]);
    #pragma unroll
    for (int m = 0; m < 4; ++m) {
        #pragma unroll
        for (int n = 0; n < 4; ++n) {
            int col = cbase + n * 16 + l15;
            float bn = cb[col], wnn = cwn[col];
            #pragma unroll
            for (int reg = 0; reg < 4; ++reg) {
                int row = rbase + m * 16 + quad * 4 + reg;
                float dnb = acc[m][n][reg];
                float dot = dnb + bn;
                float dist = wnn + xn2[row] - 2.f * dnb;
                h3[(size_t)row * CM_ + col] = f2bf(scale * dot * dot / (dist + EPSY));
            }
        }
    }
}

// k2: x1b = bf16(x + w2 . h1[b]^T + b2); fused xn2 row-norm atomics (R9 core).
__global__ __launch_bounds__(256) void k2_token_out(
    const u16* __restrict__ w2b, const u16* __restrict__ h1,
    const float* __restrict__ b2, const float* __restrict__ x,
    float* __restrict__ xn2, u16* __restrict__ x1b) {
    const int m0 = blockIdx.x * 128, n0 = blockIdx.y * 128;
    const u16* Bz = h1 + (size_t)blockIdx.z * C_ * TM_;
    MFMA_CORE(w2b + (size_t)m0 * TM_, Bz + (size_t)n0 * TM_, TM_, TM_, TM_ / 32)
    const float* rz = x + (size_t)blockIdx.z * P_ * C_;
    u16* oz = x1b + (size_t)blockIdx.z * P_ * C_;
    float* xrow = xn2 + (size_t)blockIdx.z * P_;
    #pragma unroll
    for (int i = 0; i < 4; ++i) {
        #pragma unroll
        for (int reg = 0; reg < 4; ++reg) {
            int row = rbase + i * 16 + quad * 4 + reg;
            if (row < P_) {
                float bm = b2[row];
                float s = 0.f;
                #pragma unroll
                for (int j = 0; j < 4; ++j) {
                    int col = cbase + j * 16 + l15;
                    float v = acc[i][j][reg] + bm + rz[(size_t)row * C_ + col];
                    u16 h = f2bf(v);
                    oz[(size_t)row * C_ + col] = h;
                    float vb = bf2f(h);
                    s = fmaf(vb, vb, s);
                }
                s += __shfl_xor(s, 1, 64);
                s += __shfl_xor(s, 2, 64);
                s += __shfl_xor(s, 4, 64);
                s += __shfl_xor(s, 8, 64);
                if (l15 == 0) atomicAdd(&xrow[row], s);
            }
        }
    }
}

// k4 split-K on the 4-wave 128² core: grid (8,13,6*nsplit):
// mt = x + y*8 (guard <98), n0 = (z%6)*128, ks = z/6.
__global__ __launch_bounds__(256) void k4_split(
    const u16* __restrict__ h3, const u16* __restrict__ w4b,
    u16* __restrict__ pbuf, int KK) {
    __shared__ __align__(16) u16 smem[32768];
    const int mt = blockIdx.x + blockIdx.y * 8;
    if (mt >= (B_ * P_) / 128) return;
    const int m0 = mt * 128;
    const int nz = blockIdx.z;
    const int n0 = (nz % (C_ / 128)) * 128;
    const int ks = nz / (C_ / 128);
    const int kbase = ks * KK;
    const int t = threadIdx.x;
    const int w = t >> 6, l = t & 63;
    const int wr = w >> 1, wc = w & 1;
    const int quad = l >> 4, l15 = l & 15;
    f32x4 acc[4][4];
    #pragma unroll
    for (int m = 0; m < 4; ++m)
        #pragma unroll
        for (int n = 0; n < 4; ++n) acc[m][n] = (f32x4){0.f, 0.f, 0.f, 0.f};
    mfma128_8p(h3 + (size_t)m0 * CM_ + kbase, w4b + (size_t)n0 * CM_ + kbase,
               CM_, CM_, KK / 64, acc, smem);
    const int rbase = m0 + wr * 64;
    const int cbase = n0 + wc * 64;
    u16* dst = pbuf + (size_t)ks * ((size_t)B_ * P_ * C_);
    #pragma unroll
    for (int m = 0; m < 4; ++m) {
        #pragma unroll
        for (int n = 0; n < 4; ++n) {
            int col = cbase + n * 16 + l15;
            #pragma unroll
            for (int reg = 0; reg < 4; ++reg) {
                int row = rbase + m * 16 + quad * 4 + reg;
                dst[(size_t)row * C_ + col] = f2bf(acc[m][n][reg]);
            }
        }
    }
}

// reduce: out = sum(bf16 pbuf[0..NS-1]) + bf2f(x1b) + b4
template <int NS>
__global__ __launch_bounds__(256) void k4_reduce(
    float* __restrict__ outp, const u16* __restrict__ pbuf,
    const u16* __restrict__ x1b, const float* __restrict__ b4) {
    int idx = blockIdx.x * 256 + threadIdx.x;      // < B*P*C/4
    int c = (idx * 4) % C_;
    ushort4 r = ((const ushort4*)x1b)[idx];
    float4 o;
    o.x = bf2f(r.x) + b4[c + 0];
    o.y = bf2f(r.y) + b4[c + 1];
    o.z = bf2f(r.z) + b4[c + 2];
    o.w = bf2f(r.w) + b4[c + 3];
    const size_t stride4 = (size_t)B_ * P_ * C_ / 4;
    #pragma unroll
    for (int s = 0; s < NS; ++s) {
        ushort4 p = ((const ushort4*)pbuf)[idx + s * stride4];
        o.x += bf2f(p.x); o.y += bf2f(p.y); o.z += bf2f(p.z); o.w += bf2f(p.w);
    }
    ((float4*)outp)[idx] = o;
}

// fallback k4 (tiny ws): 128x64 tile BK=32
__global__ __launch_bounds__(256) void gemm_k4_fb(
    const u16* __restrict__ A, const u16* __restrict__ Bmat,
    const float* __restrict__ biasN, const u16* __restrict__ resB,
    float* __restrict__ Fout) {
    __shared__ u16 As[128 * 32];
    __shared__ u16 Bs[64 * 32];
    const int t = threadIdx.x;
    const int wid = t >> 6, lane = t & 63;
    const int quad = lane >> 4, l15 = lane & 15;
    const int m0 = blockIdx.x * 128, n0 = blockIdx.y * 64;
    f32x4 acc[4][2];
    #pragma unroll
    for (int i = 0; i < 4; ++i)
        #pragma unroll
        for (int j = 0; j < 2; ++j) acc[i][j] = (f32x4){0.f, 0.f, 0.f, 0.f};
    const u16* Aw = As + (wid >> 1) * (64 * 32);
    const u16* Bw = Bs + (wid & 1) * (32 * 32);
    const int arow = t >> 2, akc = (t & 3) * 8;
    for (int k0 = 0; k0 < CM_; k0 += 32) {
        gl_lds16(A + (size_t)(m0 + arow) * CM_ + k0 + akc,      As + wid * 512);
        gl_lds16(A + (size_t)(m0 + 64 + arow) * CM_ + k0 + akc, As + 2048 + wid * 512);
        gl_lds16(Bmat + (size_t)(n0 + arow) * CM_ + k0 + akc,   Bs + wid * 512);
        __syncthreads();
        bf16x8 af[4], bfr[2];
        #pragma unroll
        for (int i = 0; i < 4; ++i)
            af[i] = *(const bf16x8*)(Aw + ((i * 16 + l15) * 32 + quad * 8));
        #pragma unroll
        for (int j = 0; j < 2; ++j)
            bfr[j] = *(const bf16x8*)(Bw + ((j * 16 + l15) * 32 + quad * 8));
        #pragma unroll
        for (int i = 0; i < 4; ++i)
            #pragma unroll
            for (int j = 0; j < 2; ++j)
                acc[i][j] = __builtin_amdgcn_mfma_f32_16x16x32_bf16(af[i], bfr[j], acc[i][j], 0, 0, 0);
        __syncthreads();
    }
    const int rbase = m0 + (wid >> 1) * 64;
    const int cbase = n0 + (wid & 1) * 32;
    #pragma unroll
    for (int i = 0; i < 4; ++i) {
        #pragma unroll
        for (int j = 0; j < 2; ++j) {
            int col = cbase + j * 16 + l15;
            float bn = biasN[col];
            #pragma unroll
            for (int reg = 0; reg < 4; ++reg) {
                int row = rbase + i * 16 + quad * 4 + reg;
                float v = acc[i][j][reg] + bn + bf2f(resB[(size_t)row * C_ + col]);
                Fout[(size_t)row * C_ + col] = v;
            }
        }
    }
}

extern "C" void kernel_launch(void* const* d_in, const int* in_sizes, int n_in,
                              void* d_out, int out_size, void* d_ws, size_t ws_size,
                              hipStream_t stream) {
    const float* x  = (const float*)d_in[0];
    const float* tw = (const float*)d_in[1];
    const float* tb = (const float*)d_in[2];
    const float* ta = (const float*)d_in[3];
    const float* w2 = (const float*)d_in[4];
    const float* b2 = (const float*)d_in[5];
    const float* cw = (const float*)d_in[6];
    const float* cb = (const float*)d_in[7];
    const float* ca = (const float*)d_in[8];
    const float* w4 = (const float*)d_in[9];
    const float* b4 = (const float*)d_in[10];
    float* out = (float*)d_out;

    // ---- workspace layout (aliased) ----
    char* ws = (char*)d_ws;
    u16* h1 = (u16*)ws;                                    // B*C*TM (37.7 MB)
    u16* xT = (u16*)(ws + 37748736);                       // (B*C) x 224 (22 MB)
    u16* h3 = (u16*)ws;                                    // (B*P) x CM (77 MB)
    size_t off = 77070336;
    u16* x1b = (u16*)(ws + off); off += (size_t)B_ * P_ * C_ * 2;
    u16* twb = (u16*)(ws + off); off += (size_t)TM_ * PPAD * 2;
    u16* w2b = (u16*)(ws + off); off += (size_t)256 * TM_ * 2;
    u16* cwb = (u16*)(ws + off); off += (size_t)CM_ * C_ * 2;
    u16* w4b = (u16*)(ws + off); off += (size_t)C_ * CM_ * 2;
    float* xn1 = (float*)(ws + off); off += (size_t)B_ * C_ * 4;
    float* xn2 = (float*)(ws + off); off += (size_t)B_ * P_ * 4;
    float* twn = (float*)(ws + off); off += (size_t)TM_ * 4;
    float* cwn = (float*)(ws + off); off += (size_t)CM_ * 4;
    u16* pbuf = (u16*)(ws + off);                          // bf16 split-K partials
    const size_t psz = (size_t)B_ * P_ * C_ * 2;           // 19,267,584 per buffer

    int nsplit = 1;
    if (ws_size >= off + 4 * psz)      nsplit = 4;
    else if (ws_size >= off + 2 * psz) nsplit = 2;

    const float SBT = (float)TM_ / logf((float)TM_ + 1.0f);
    const float SBC = (float)CM_ / logf((float)CM_ + 1.0f);

    // ---- prep ----
    hipMemsetAsync(xn1, 0, (size_t)(B_ * C_ + B_ * P_) * 4, stream);
    k_prep_weights<<<3552, 256, 0, stream>>>(tw, twb, twn, cw, cwb, cwn,
                                             w2, w2b, w4, w4b);
    k_prep_xT<<<dim3(PPAD / 32, C_ / 32, B_), 256, 0, stream>>>(x, xT, xn1);

    // ---- k1: M=49152 N=384 K=224 ; XCD-swizzled grid (8,48,3) ----
    k1_token_yat<<<dim3(8, 48, 3), 256, 0, stream>>>(
        xT, twb, tb, twn, xn1, ta, SBT, h1);

    // ---- k2: M=256 N=768 K=384, per-batch ----
    k2_token_out<<<dim3(2, C_ / 128, B_), 256, 0, stream>>>(
        w2b, h1, b2, x, xn2, x1b);

    // ---- k3: M=12544 N=3072 K=768 ; 4-wave 128² 8-phase, grid (8,13,24) ----
    k3_chan_yat<<<dim3(8, 13, 24), 256, 0, stream>>>(
        x1b, cwb, cb, cwn, xn2, ca, SBC, h3);

    // ---- k4: M=12544 N=768 K=3072, split-K bf16 partials, 4-wave core ----
    if (nsplit > 1) {
        k4_split<<<dim3(8, 13, (C_ / 128) * nsplit), 256, 0, stream>>>(
            h3, w4b, pbuf, CM_ / nsplit);
        int n4 = B_ * P_ * C_ / 4;
        if (nsplit == 4)
            k4_reduce<4><<<(n4 + 255) / 256, 256, 0, stream>>>(out, pbuf, x1b, b4);
        else
            k4_reduce<2><<<(n4 + 255) / 256, 256, 0, stream>>>(out, pbuf, x1b, b4);
    } else {
        gemm_k4_fb<<<dim3(B_ * P_ / 128, C_ / 64), 256, 0, stream>>>(
            h3, w4b, b4, x1b, out);
    }
}